// Round 1
// baseline (321.594 us; speedup 1.0000x reference)
//
#include <hip/hip_runtime.h>
#include <hip/hip_bf16.h>
#include <stdint.h>

// Problem constants (B=2, T=2048, D=2048, H=16, HD=128, ALPHA=1.0)
#define BT    4096          // B*T rows
#define DM    2048          // d_model
#define TSEQ  2048
#define NH    16
#define HD    128
#define ATT_SCALE 0.088388347648318447f   // 128^-0.5

// Window: decay is -(i-j); weights beyond delta=63 are < e^-63 -> negligible.
#define WIN   64
#define IB    32            // output rows per attention block
#define WROWS 96            // staged window rows = IB + WIN
#define LDQ   136           // padded LDS stride (bf16 elems), 16B-aligned rows

typedef __attribute__((ext_vector_type(8))) short short8;
typedef __attribute__((ext_vector_type(4))) float f32x4;

__device__ __forceinline__ float bflo(uint32_t u) { return __uint_as_float(u << 16); }
__device__ __forceinline__ float bfhi(uint32_t u) { return __uint_as_float(u & 0xFFFF0000u); }
__device__ __forceinline__ uint16_t f2bf(float f) {
  uint32_t u = __float_as_uint(f);
  return (uint16_t)((u + 0x7FFFu + ((u >> 16) & 1u)) >> 16);  // RNE
}

__device__ __forceinline__ void gload_lds16(const void* g, void* l) {
  __builtin_amdgcn_global_load_lds((__attribute__((address_space(1))) void*)g,
                                   (__attribute__((address_space(3))) void*)l,
                                   16, 0, 0);
}

// ---------------- fp32 -> bf16 cast ----------------
__global__ __launch_bounds__(256) void cast_f32_bf16(const float* __restrict__ in,
                                                     uint16_t* __restrict__ out, int n4) {
  int i = blockIdx.x * 256 + threadIdx.x;
  int stride = gridDim.x * 256;
  for (; i < n4; i += stride) {
    float4 v = ((const float4*)in)[i];
    ushort4 o;
    o.x = f2bf(v.x); o.y = f2bf(v.y); o.z = f2bf(v.z); o.w = f2bf(v.w);
    ((ushort4*)out)[i] = o;
  }
}

// ---------------- bf16 GEMM: C[M,N] = A[M,K] @ B[N,K]^T + bias[N] ----------------
// m97 structure: 128x128 tile, BK=64, 4 waves 2x2, global_load_lds width 16,
// mfma_f32_16x16x32_bf16 fragments (A/B: row=lane&15, k=(lane>>4)*8+i;
// C/D: col=lane&15, row=(lane>>4)*4+reg  [m89-verified]).
template <bool OUT_BF16>
__global__ __launch_bounds__(256) void gemm_bt(const uint16_t* __restrict__ A,
                                               const uint16_t* __restrict__ B,
                                               const float* __restrict__ bias,
                                               void* __restrict__ Cout,
                                               int M, int N, int K) {
  __shared__ __align__(16) uint16_t As[128][64];
  __shared__ __align__(16) uint16_t Bs[128][64];

  const int tid  = threadIdx.x;
  const int lane = tid & 63;
  const int wid  = tid >> 6;
  const int wr   = wid >> 1, wc = wid & 1;
  const int m0   = blockIdx.y * 128, n0 = blockIdx.x * 128;

  f32x4 acc[4][4];
#pragma unroll
  for (int i = 0; i < 4; ++i)
#pragma unroll
    for (int j = 0; j < 4; ++j) acc[i][j] = (f32x4){0.f, 0.f, 0.f, 0.f};

  for (int kt = 0; kt < K; kt += 64) {
    // stage 128x64 bf16 A-tile + B-tile: 16KB each, 1KB per (wave,issue)
#pragma unroll
    for (int q = 0; q < 4; ++q) {
      int iq  = (wid * 4 + q) * 64 + lane;   // 16B-chunk linear index
      int row = iq >> 3;
      int col = (iq & 7) << 3;
      const uint16_t* ga = A + (size_t)(m0 + row) * K + kt + col;
      const uint16_t* gb = B + (size_t)(n0 + row) * K + kt + col;
      char* la = (char*)&As[0][0] + (size_t)(wid * 4 + q) * 1024;
      char* lb = (char*)&Bs[0][0] + (size_t)(wid * 4 + q) * 1024;
      gload_lds16(ga, la);
      gload_lds16(gb, lb);
    }
    __syncthreads();   // drains vmcnt for global_load_lds

#pragma unroll
    for (int kk = 0; kk < 2; ++kk) {
      short8 af[4], bf[4];
#pragma unroll
      for (int t = 0; t < 4; ++t) {
        af[t] = *(const short8*)&As[wr * 64 + t * 16 + (lane & 15)][kk * 32 + (lane >> 4) * 8];
        bf[t] = *(const short8*)&Bs[wc * 64 + t * 16 + (lane & 15)][kk * 32 + (lane >> 4) * 8];
      }
#pragma unroll
      for (int i = 0; i < 4; ++i)
#pragma unroll
        for (int j = 0; j < 4; ++j)
          acc[i][j] = __builtin_amdgcn_mfma_f32_16x16x32_bf16(af[i], bf[j], acc[i][j], 0, 0, 0);
    }
    __syncthreads();
  }

  const int rbase = m0 + wr * 64 + ((lane >> 4) << 2);
  const int cbase = n0 + wc * 64 + (lane & 15);
#pragma unroll
  for (int i = 0; i < 4; ++i)
#pragma unroll
    for (int j = 0; j < 4; ++j) {
      int c = cbase + j * 16;
      float bv = bias[c];
#pragma unroll
      for (int r = 0; r < 4; ++r) {
        int rr = rbase + i * 16 + r;
        float val = acc[i][j][r] + bv;
        if (OUT_BF16)
          ((uint16_t*)Cout)[(size_t)rr * N + c] = f2bf(val);
        else
          ((float*)Cout)[(size_t)rr * N + c] = val;
      }
    }
}

// ---------------- windowed causal attention ----------------
// Per reference: S[i,j] = K_i . Q_j * scale - (i-j), mask j>i, softmax over j,
// O_i = sum_j P[i,j] V_j.  Window j in [i-63, i]; tail < e^-63 (negligible).
// Block: 256 threads (4 waves), 32 rows; wave w handles rows w*8..w*8+7.
__global__ __launch_bounds__(256) void attn_win(const uint16_t* __restrict__ Q,
                                                const uint16_t* __restrict__ K,
                                                const uint16_t* __restrict__ V,
                                                uint16_t* __restrict__ O) {
  __shared__ __align__(16) uint16_t Qs[WROWS][LDQ];
  __shared__ __align__(16) uint16_t Vs[WROWS][LDQ];
  __shared__ __align__(16) uint16_t Ks[IB][LDQ];
  __shared__ float sbuf[4][WIN];

  const int i0 = blockIdx.x * IB;
  const int h  = blockIdx.y;
  const int b  = blockIdx.z;
  const int wb = i0 - (WIN - 1);                       // global j of window row 0
  const size_t base = ((size_t)b * TSEQ) * DM + (size_t)h * HD;
  const int tid = threadIdx.x;

  // stage Q,V window rows [wb, wb+95] (zero-fill OOB), K rows [i0, i0+31]
  for (int c = tid; c < WROWS * 16; c += 256) {
    int row = c >> 4, c8 = c & 15;
    int j = wb + row;
    uint4 vq = {0, 0, 0, 0}, vv = {0, 0, 0, 0};
    if (j >= 0 && j < TSEQ) {
      const size_t off = base + (size_t)j * DM + c8 * 8;
      vq = *(const uint4*)(Q + off);
      vv = *(const uint4*)(V + off);
    }
    *(uint4*)&Qs[row][c8 * 8] = vq;
    *(uint4*)&Vs[row][c8 * 8] = vv;
  }
  for (int c = tid; c < IB * 16; c += 256) {
    int row = c >> 4, c8 = c & 15;
    const size_t off = base + (size_t)(i0 + row) * DM + c8 * 8;
    *(uint4*)&Ks[row][c8 * 8] = *(const uint4*)(K + off);
  }
  __syncthreads();

  const int lane = tid & 63;
  const int w    = tid >> 6;
  const int g    = lane >> 2;     // j-group 0..15
  const int sub  = lane & 3;      // 32-dim chunk

  for (int rr = 0; rr < IB / 4; ++rr) {
    const int il = w * 8 + rr;
    const int i  = i0 + il;
    const int lim = 63 - i;       // jj >= lim is valid (j >= 0)

    // K row chunk -> regs (fp32)
    float kreg[32];
    {
      const uint16_t* kp = &Ks[il][sub * 32];
#pragma unroll
      for (int c = 0; c < 4; ++c) {
        uint4 kv = *(const uint4*)(kp + c * 8);
        uint32_t wd[4] = {kv.x, kv.y, kv.z, kv.w};
#pragma unroll
        for (int t = 0; t < 4; ++t) {
          kreg[c * 8 + 2 * t]     = bflo(wd[t]);
          kreg[c * 8 + 2 * t + 1] = bfhi(wd[t]);
        }
      }
    }

    // scores: 16 j's per pass x 4 passes; 4 lanes per j over 128 dims
#pragma unroll
    for (int p = 0; p < 4; ++p) {
      int jj   = p * 16 + g;
      int jrow = il + jj;
      const uint16_t* qp = &Qs[jrow][sub * 32];
      float s = 0.f;
#pragma unroll
      for (int c = 0; c < 4; ++c) {
        uint4 qv = *(const uint4*)(qp + c * 8);
        uint32_t wd[4] = {qv.x, qv.y, qv.z, qv.w};
#pragma unroll
        for (int t = 0; t < 4; ++t) {
          s += kreg[c * 8 + 2 * t]     * bflo(wd[t]);
          s += kreg[c * 8 + 2 * t + 1] * bfhi(wd[t]);
        }
      }
      s += __shfl_xor(s, 1);
      s += __shfl_xor(s, 2);
      float sv = (jj >= lim) ? (s * ATT_SCALE - (float)(63 - jj)) : -1e30f;
      if (sub == 0) sbuf[w][jj] = sv;
    }
    asm volatile("s_waitcnt lgkmcnt(0)" ::: "memory");

    // softmax over the 64 window slots (one per lane)
    float sv = sbuf[w][lane];
    float m = sv;
#pragma unroll
    for (int off = 32; off; off >>= 1) m = fmaxf(m, __shfl_xor(m, off));
    float pl = __expf(sv - m);
    float denom = pl;
#pragma unroll
    for (int off = 32; off; off >>= 1) denom += __shfl_xor(denom, off);
    sbuf[w][lane] = pl;
    asm volatile("s_waitcnt lgkmcnt(0)" ::: "memory");

    // PV: lane owns dims {2*lane, 2*lane+1}
    float o0 = 0.f, o1 = 0.f;
    const int d0 = lane * 2;
#pragma unroll 8
    for (int jj = 0; jj < WIN; ++jj) {
      float p = sbuf[w][jj];
      uint32_t vv = *(const uint32_t*)&Vs[il + jj][d0];
      o0 += p * bflo(vv);
      o1 += p * bfhi(vv);
    }
    float inv = 1.0f / denom;
    o0 *= inv;
    o1 *= inv;
    uint32_t uo = (uint32_t)f2bf(o0) | ((uint32_t)f2bf(o1) << 16);
    *(uint32_t*)&O[base + (size_t)i * DM + d0] = uo;
  }
}

// ---------------- launch ----------------
extern "C" void kernel_launch(void* const* d_in, const int* in_sizes, int n_in,
                              void* d_out, int out_size, void* d_ws, size_t ws_size,
                              hipStream_t stream) {
  const float* x   = (const float*)d_in[0];
  const float* q_w = (const float*)d_in[1];
  const float* q_b = (const float*)d_in[2];
  const float* k_w = (const float*)d_in[3];
  const float* k_b = (const float*)d_in[4];
  const float* v_w = (const float*)d_in[5];
  const float* v_b = (const float*)d_in[6];
  const float* o_w = (const float*)d_in[7];
  const float* o_b = (const float*)d_in[8];

  char* ws = (char*)d_ws;
  const size_t XB_BYTES = (size_t)BT * DM * 2;        // 16.78 MB
  const size_t W_BYTES  = (size_t)DM * DM * 2;        //  8.39 MB
  uint16_t* xb = (uint16_t*)(ws);                     // x bf16; later reused for attn out
  uint16_t* wq = (uint16_t*)(ws + XB_BYTES);
  uint16_t* wk = (uint16_t*)(ws + XB_BYTES + W_BYTES);
  uint16_t* wv = (uint16_t*)(ws + XB_BYTES + 2 * W_BYTES);
  uint16_t* wo = (uint16_t*)(ws + XB_BYTES + 3 * W_BYTES);
  uint16_t* Qb = (uint16_t*)(ws + XB_BYTES + 4 * W_BYTES);
  uint16_t* Kb = Qb + (size_t)BT * DM;
  uint16_t* Vb = Kb + (size_t)BT * DM;

  cast_f32_bf16<<<2048, 256, 0, stream>>>(x,   xb, BT * DM / 4);
  cast_f32_bf16<<<1024, 256, 0, stream>>>(q_w, wq, DM * DM / 4);
  cast_f32_bf16<<<1024, 256, 0, stream>>>(k_w, wk, DM * DM / 4);
  cast_f32_bf16<<<1024, 256, 0, stream>>>(v_w, wv, DM * DM / 4);
  cast_f32_bf16<<<1024, 256, 0, stream>>>(o_w, wo, DM * DM / 4);

  dim3 gg(DM / 128, BT / 128);   // (16, 32)
  gemm_bt<true><<<gg, 256, 0, stream>>>(xb, wq, q_b, Qb, BT, DM, DM);
  gemm_bt<true><<<gg, 256, 0, stream>>>(xb, wk, k_b, Kb, BT, DM, DM);
  gemm_bt<true><<<gg, 256, 0, stream>>>(xb, wv, v_b, Vb, BT, DM, DM);

  dim3 ga(TSEQ / IB, NH, 2);     // (64, 16, 2)
  attn_win<<<ga, 256, 0, stream>>>(Qb, Kb, Vb, xb);  // attn out -> xb (free now)

  gemm_bt<false><<<gg, 256, 0, stream>>>(xb, wo, o_b, d_out, BT, DM, DM);
}

// Round 2
// 248.349 us; speedup vs baseline: 1.2949x; 1.2949x over previous
//
#include <hip/hip_runtime.h>
#include <hip/hip_bf16.h>
#include <stdint.h>

// Problem constants (B=2, T=2048, D=2048, H=16, HD=128, ALPHA=1.0)
#define BT    4096          // B*T rows
#define DM    2048          // d_model
#define TSEQ  2048
#define NH    16
#define HD    128
#define QKV_LD 6144         // fused QKV output row stride
#define ATT_SCALE 0.088388347648318447f   // 128^-0.5

// decay is -(i-j); weights beyond delta=63 are < e^-60 -> negligible (validated R1: absmax 0.0156)
#define WIN   64

typedef __attribute__((ext_vector_type(8))) short short8;
typedef __attribute__((ext_vector_type(4))) float f32x4;

__device__ __forceinline__ uint16_t f2bf(float f) {
  uint32_t u = __float_as_uint(f);
  return (uint16_t)((u + 0x7FFFu + ((u >> 16) & 1u)) >> 16);  // RNE
}

__device__ __forceinline__ void gload_lds16(const void* g, void* l) {
  __builtin_amdgcn_global_load_lds((__attribute__((address_space(1))) void*)g,
                                   (__attribute__((address_space(3))) void*)l,
                                   16, 0, 0);
}

// ---------------- fp32 -> bf16 cast ----------------
__global__ __launch_bounds__(256) void cast_f32_bf16(const float* __restrict__ in,
                                                     uint16_t* __restrict__ out, int n4) {
  int i = blockIdx.x * 256 + threadIdx.x;
  int stride = gridDim.x * 256;
  for (; i < n4; i += stride) {
    float4 v = ((const float4*)in)[i];
    ushort4 o;
    o.x = f2bf(v.x); o.y = f2bf(v.y); o.z = f2bf(v.z); o.w = f2bf(v.w);
    ((ushort4*)out)[i] = o;
  }
}

// ---------------- concat 3 bias vectors ----------------
__global__ __launch_bounds__(256) void concat3(const float* __restrict__ a,
                                               const float* __restrict__ b,
                                               const float* __restrict__ c,
                                               float* __restrict__ out) {
  int i = blockIdx.x * 256 + threadIdx.x;   // 6144 threads
  float v = (i < DM) ? a[i] : ((i < 2 * DM) ? b[i - DM] : c[i - 2 * DM]);
  out[i] = v;
}

// ---------------- bf16 GEMM: C[M,N] = A[M,K] @ B[N,K]^T + bias[N] ----------------
// m97 structure (verified R1 ~760 TF): 128x128 tile, BK=64, 4 waves 2x2.
template <bool OUT_BF16>
__global__ __launch_bounds__(256) void gemm_bt(const uint16_t* __restrict__ A,
                                               const uint16_t* __restrict__ B,
                                               const float* __restrict__ bias,
                                               void* __restrict__ Cout,
                                               int M, int N, int K) {
  __shared__ __align__(16) uint16_t As[128][64];
  __shared__ __align__(16) uint16_t Bs[128][64];

  const int tid  = threadIdx.x;
  const int lane = tid & 63;
  const int wid  = tid >> 6;
  const int wr   = wid >> 1, wc = wid & 1;
  const int m0   = blockIdx.y * 128, n0 = blockIdx.x * 128;

  f32x4 acc[4][4];
#pragma unroll
  for (int i = 0; i < 4; ++i)
#pragma unroll
    for (int j = 0; j < 4; ++j) acc[i][j] = (f32x4){0.f, 0.f, 0.f, 0.f};

  for (int kt = 0; kt < K; kt += 64) {
#pragma unroll
    for (int q = 0; q < 4; ++q) {
      int iq  = (wid * 4 + q) * 64 + lane;
      int row = iq >> 3;
      int col = (iq & 7) << 3;
      const uint16_t* ga = A + (size_t)(m0 + row) * K + kt + col;
      const uint16_t* gb = B + (size_t)(n0 + row) * K + kt + col;
      char* la = (char*)&As[0][0] + (size_t)(wid * 4 + q) * 1024;
      char* lb = (char*)&Bs[0][0] + (size_t)(wid * 4 + q) * 1024;
      gload_lds16(ga, la);
      gload_lds16(gb, lb);
    }
    __syncthreads();

#pragma unroll
    for (int kk = 0; kk < 2; ++kk) {
      short8 af[4], bf[4];
#pragma unroll
      for (int t = 0; t < 4; ++t) {
        af[t] = *(const short8*)&As[wr * 64 + t * 16 + (lane & 15)][kk * 32 + (lane >> 4) * 8];
        bf[t] = *(const short8*)&Bs[wc * 64 + t * 16 + (lane & 15)][kk * 32 + (lane >> 4) * 8];
      }
#pragma unroll
      for (int i = 0; i < 4; ++i)
#pragma unroll
        for (int j = 0; j < 4; ++j)
          acc[i][j] = __builtin_amdgcn_mfma_f32_16x16x32_bf16(af[i], bf[j], acc[i][j], 0, 0, 0);
    }
    __syncthreads();
  }

  const int rbase = m0 + wr * 64 + ((lane >> 4) << 2);
  const int cbase = n0 + wc * 64 + (lane & 15);
#pragma unroll
  for (int i = 0; i < 4; ++i)
#pragma unroll
    for (int j = 0; j < 4; ++j) {
      int c = cbase + j * 16;
      float bv = bias[c];
#pragma unroll
      for (int r = 0; r < 4; ++r) {
        int rr = rbase + i * 16 + r;
        float val = acc[i][j][r] + bv;
        if (OUT_BF16)
          ((uint16_t*)Cout)[(size_t)rr * N + c] = f2bf(val);
        else
          ((float*)Cout)[(size_t)rr * N + c] = val;
      }
    }
}

// ---------------- MFMA windowed causal attention ----------------
// Reference: S[i,j] = K_i . Q_j * scale - (i-j) (K is the row operand!), mask j>i,
// softmax over j, O_i = sum_j P[i,j] V_j.  Window j in [i-63, i].
// Block: 64 output rows (i0..i0+63), 4 waves x 16 rows. Staged window rows
// r=0..127 <-> j = i0-63+r.  For i=i0+il: valid r in [il, il+63], delta = il+63-r.
// LDS: Qs[128][128] (chunk-XOR swizzled, global_load_lds) | Vt[128][136] (transposed)
//      P[64][136] aliases Qs after a barrier.
__global__ __launch_bounds__(256) void attn_mfma(const uint16_t* __restrict__ QKV,
                                                 uint16_t* __restrict__ O) {
  __shared__ __align__(16) uint16_t sm[16384 + 17408];   // 67.6 KB -> 2 blocks/CU
  uint16_t* Qs = sm;              // [128][128] linear, chunk-swizzled
  uint16_t* Vt = sm + 16384;      // [128 d][136 j]
  uint16_t* Pl = sm;              // [64][136], aliases Qs after barrier

  const int tid  = threadIdx.x;
  const int lane = tid & 63;
  const int w    = tid >> 6;
  const int g    = lane >> 4;     // 0..3
  const int ln   = lane & 15;

  const int i0 = blockIdx.x * 64;
  const int h  = blockIdx.y;
  const int b  = blockIdx.z;
  const int wb = i0 - 63;
  const size_t hoff  = (size_t)h * HD;
  const size_t bbase = (size_t)b * TSEQ;

  // ---- stage Q window (cols 0..2047 of QKV) with chunk-XOR swizzle ----
  // LDS chunk (row,c) holds global chunk (c ^ (row&7)); read side applies same XOR.
#pragma unroll
  for (int it = 0; it < 8; ++it) {
    int s   = it * 256 + tid;
    int row = s >> 4, c = s & 15;
    int j = wb + row;
    if (j >= 0 && j < TSEQ) {
      const uint16_t* gsrc = QKV + (bbase + j) * (size_t)QKV_LD + hoff
                           + (size_t)((c ^ (row & 7)) * 8);
      uint16_t* ldst = Qs + (size_t)(s & ~63) * 8;   // wave-uniform base; HW adds lane*16B
      gload_lds16(gsrc, ldst);
    } else {
      uint4 z = {0, 0, 0, 0};
      *(uint4*)(Qs + (size_t)s * 8) = z;
    }
  }

  // ---- stage V transposed: Vt[d][j] (V = cols 4096..6143 of QKV) ----
#pragma unroll
  for (int it = 0; it < 4; ++it) {
    int s  = it * 256 + tid;
    int jp = (s & 15) | (it << 4);        // 0..63 (pair of j rows)
    int dc = (s >> 4) & 15;               // d chunk of 8
    int j0 = wb + 2 * jp;
    uint4 va = {0, 0, 0, 0}, vb = {0, 0, 0, 0};
    if (j0 >= 0 && j0 < TSEQ)
      va = *(const uint4*)(QKV + (bbase + j0) * (size_t)QKV_LD + 2 * DM + hoff + dc * 8);
    if (j0 + 1 >= 0 && j0 + 1 < TSEQ)
      vb = *(const uint4*)(QKV + (bbase + j0 + 1) * (size_t)QKV_LD + 2 * DM + hoff + dc * 8);
    const uint16_t* ap = (const uint16_t*)&va;
    const uint16_t* bp = (const uint16_t*)&vb;
#pragma unroll
    for (int t = 0; t < 8; ++t) {
      uint32_t pk = (uint32_t)ap[t] | ((uint32_t)bp[t] << 16);
      *(uint32_t*)(Vt + (size_t)(dc * 8 + t) * 136 + 2 * jp) = pk;
    }
  }

  // ---- K rows of this wave -> registers (A operand; cols 2048..4095) ----
  short8 kreg[4];
  {
    const uint16_t* kp = QKV + (bbase + i0 + w * 16 + ln) * (size_t)QKV_LD
                       + DM + hoff + g * 8;
#pragma unroll
    for (int kc = 0; kc < 4; ++kc) kreg[kc] = *(const short8*)(kp + kc * 32);
  }

  __syncthreads();   // drains gload_lds vmcnt + ds writes

  // ---- QK^T: S[16][128] per wave, 32 MFMAs ----
  f32x4 acc[8];
#pragma unroll
  for (int nf = 0; nf < 8; ++nf) acc[nf] = (f32x4){0.f, 0.f, 0.f, 0.f};
#pragma unroll
  for (int kc = 0; kc < 4; ++kc) {
#pragma unroll
    for (int nf = 0; nf < 8; ++nf) {
      int row = nf * 16 + ln;
      int chunk = (kc * 4 + g) ^ (row & 7);
      short8 qf = *(const short8*)(Qs + (size_t)row * 128 + chunk * 8);
      acc[nf] = __builtin_amdgcn_mfma_f32_16x16x32_bf16(kreg[kc], qf, acc[nf], 0, 0, 0);
    }
  }

  // ---- scale + decay + causal/window mask (C/D layout: col=ln, row=g*4+r) ----
#pragma unroll
  for (int nf = 0; nf < 8; ++nf) {
    int rj = nf * 16 + ln;
    int jg = wb + rj;
#pragma unroll
    for (int r = 0; r < 4; ++r) {
      int il = w * 16 + g * 4 + r;
      int delta = il + 63 - rj;
      float v = acc[nf][r] * ATT_SCALE - (float)delta;
      acc[nf][r] = ((unsigned)delta < 64u && jg >= 0) ? v : -1e30f;
    }
  }

  // ---- softmax over window cols (in-lane over 8 frags + shfl over 16 lanes) ----
  float inv[4];
#pragma unroll
  for (int r = 0; r < 4; ++r) {
    float mx = acc[0][r];
#pragma unroll
    for (int nf = 1; nf < 8; ++nf) mx = fmaxf(mx, acc[nf][r]);
    mx = fmaxf(mx, __shfl_xor(mx, 1));
    mx = fmaxf(mx, __shfl_xor(mx, 2));
    mx = fmaxf(mx, __shfl_xor(mx, 4));
    mx = fmaxf(mx, __shfl_xor(mx, 8));
    float s = 0.f;
#pragma unroll
    for (int nf = 0; nf < 8; ++nf) {
      float e = __expf(acc[nf][r] - mx);
      acc[nf][r] = e;
      s += e;
    }
    s += __shfl_xor(s, 1);
    s += __shfl_xor(s, 2);
    s += __shfl_xor(s, 4);
    s += __shfl_xor(s, 8);
    inv[r] = 1.0f / s;
  }

  __syncthreads();   // everyone done reading Qs; safe to overwrite with P

  // ---- write P (bf16) into Pl[64][136]; own rows only ----
#pragma unroll
  for (int nf = 0; nf < 8; ++nf)
#pragma unroll
    for (int r = 0; r < 4; ++r)
      Pl[(size_t)(w * 16 + g * 4 + r) * 136 + nf * 16 + ln] = f2bf(acc[nf][r]);
  asm volatile("s_waitcnt lgkmcnt(0)" ::: "memory");
  __builtin_amdgcn_sched_barrier(0);

  // ---- PV: O[16][128] per wave, 32 MFMAs (A = P own rows, B = Vt) ----
  f32x4 o[8];
#pragma unroll
  for (int nf = 0; nf < 8; ++nf) o[nf] = (f32x4){0.f, 0.f, 0.f, 0.f};
#pragma unroll
  for (int kc = 0; kc < 4; ++kc) {
    short8 pa = *(const short8*)(Pl + (size_t)(w * 16 + ln) * 136 + kc * 32 + g * 8);
#pragma unroll
    for (int nf = 0; nf < 8; ++nf) {
      short8 vbf = *(const short8*)(Vt + (size_t)(nf * 16 + ln) * 136 + kc * 32 + g * 8);
      o[nf] = __builtin_amdgcn_mfma_f32_16x16x32_bf16(pa, vbf, o[nf], 0, 0, 0);
    }
  }

  // ---- normalize + store (row = g*4+r matches softmax lane mapping) ----
  const size_t obase = (bbase + i0 + w * 16) * (size_t)DM + hoff;
#pragma unroll
  for (int nf = 0; nf < 8; ++nf)
#pragma unroll
    for (int r = 0; r < 4; ++r)
      O[obase + (size_t)(g * 4 + r) * DM + nf * 16 + ln] = f2bf(o[nf][r] * inv[r]);
}

// ---------------- launch ----------------
extern "C" void kernel_launch(void* const* d_in, const int* in_sizes, int n_in,
                              void* d_out, int out_size, void* d_ws, size_t ws_size,
                              hipStream_t stream) {
  const float* x   = (const float*)d_in[0];
  const float* q_w = (const float*)d_in[1];
  const float* q_b = (const float*)d_in[2];
  const float* k_w = (const float*)d_in[3];
  const float* k_b = (const float*)d_in[4];
  const float* v_w = (const float*)d_in[5];
  const float* v_b = (const float*)d_in[6];
  const float* o_w = (const float*)d_in[7];
  const float* o_b = (const float*)d_in[8];

  char* ws = (char*)d_ws;
  const size_t XB_BYTES   = (size_t)BT * DM * 2;        // 16.78 MB
  const size_t W_BYTES    = (size_t)DM * DM * 2;        //  8.39 MB
  const size_t WQKV_BYTES = 3 * W_BYTES;                // 25.17 MB

  uint16_t* xb    = (uint16_t*)(ws);                                  // x bf16 / attn out
  uint16_t* wqkv  = (uint16_t*)(ws + XB_BYTES);                       // [6144][2048]
  uint16_t* wo    = (uint16_t*)(ws + XB_BYTES + WQKV_BYTES);          // [2048][2048]
  float*    bcat  = (float*)   (ws + XB_BYTES + WQKV_BYTES + W_BYTES);
  uint16_t* QKVb  = (uint16_t*)(ws + XB_BYTES + WQKV_BYTES + W_BYTES + 24576); // [4096][6144]

  cast_f32_bf16<<<2048, 256, 0, stream>>>(x,   xb, BT * DM / 4);
  cast_f32_bf16<<<1024, 256, 0, stream>>>(q_w, wqkv,                xb == 0 ? 0 : DM * DM / 4);
  cast_f32_bf16<<<1024, 256, 0, stream>>>(k_w, wqkv + (size_t)DM * DM,     DM * DM / 4);
  cast_f32_bf16<<<1024, 256, 0, stream>>>(v_w, wqkv + (size_t)2 * DM * DM, DM * DM / 4);
  cast_f32_bf16<<<1024, 256, 0, stream>>>(o_w, wo, DM * DM / 4);
  concat3<<<24, 256, 0, stream>>>(q_b, k_b, v_b, bcat);

  // fused QKV projection: [4096][2048] @ [6144][2048]^T -> [4096][6144]
  dim3 gq(3 * DM / 128, BT / 128);   // (48, 32)
  gemm_bt<true><<<gq, 256, 0, stream>>>(xb, wqkv, bcat, QKVb, BT, 3 * DM, DM);

  dim3 ga(TSEQ / 64, NH, 2);         // (32, 16, 2)
  attn_mfma<<<ga, 256, 0, stream>>>(QKVb, xb);   // attn out -> xb

  dim3 go(DM / 128, BT / 128);       // (16, 32)
  gemm_bt<false><<<go, 256, 0, stream>>>(xb, wo, o_b, d_out, BT, DM, DM);
}

// Round 4
// 206.678 us; speedup vs baseline: 1.5560x; 1.2016x over previous
//
#include <hip/hip_runtime.h>
#include <hip/hip_bf16.h>
#include <stdint.h>

// Problem constants (B=2, T=2048, D=2048, H=16, HD=128, ALPHA=1.0)
#define BT    4096
#define DM    2048
#define TSEQ  2048
#define NHEAD 16
#define HD    128
#define QKV_LD 6144
#define ATT_SCALE 0.088388347648318447f   // 128^-0.5
#define WIN   64

typedef __attribute__((ext_vector_type(8))) short short8;
typedef __attribute__((ext_vector_type(4))) float f32x4;

__device__ __forceinline__ uint16_t f2bf(float f) {
  uint32_t u = __float_as_uint(f);
  return (uint16_t)((u + 0x7FFFu + ((u >> 16) & 1u)) >> 16);  // RNE
}

__device__ __forceinline__ void gload_lds16(const void* g, void* l) {
  __builtin_amdgcn_global_load_lds((__attribute__((address_space(1))) void*)g,
                                   (__attribute__((address_space(3))) void*)l,
                                   16, 0, 0);
}

// ---------------- prep: all fp32->bf16 casts + bias concat, one launch ----------------
__global__ __launch_bounds__(256) void prep(const float* __restrict__ x,
                                            const float* __restrict__ qw,
                                            const float* __restrict__ kw,
                                            const float* __restrict__ vw,
                                            const float* __restrict__ ow,
                                            const float* __restrict__ qb,
                                            const float* __restrict__ kb,
                                            const float* __restrict__ vb,
                                            uint16_t* __restrict__ xb,
                                            uint16_t* __restrict__ wqkv,
                                            uint16_t* __restrict__ wo,
                                            float* __restrict__ bcat) {
  const int NX = BT * DM / 4;
  const int NW = DM * DM / 4;
  const int total = NX + 4 * NW;
  int i0 = blockIdx.x * 256 + threadIdx.x;
  for (int idx = i0; idx < total; idx += gridDim.x * 256) {
    const float* src;
    uint16_t* dst;
    int off;
    if (idx < NX)            { src = x;  dst = xb;                          off = idx; }
    else if (idx < NX + NW)  { src = qw; dst = wqkv;                        off = idx - NX; }
    else if (idx < NX + 2*NW){ src = kw; dst = wqkv + (size_t)DM * DM;      off = idx - NX - NW; }
    else if (idx < NX + 3*NW){ src = vw; dst = wqkv + (size_t)2 * DM * DM;  off = idx - NX - 2*NW; }
    else                     { src = ow; dst = wo;                          off = idx - NX - 3*NW; }
    float4 v = ((const float4*)src)[off];
    ushort4 o;
    o.x = f2bf(v.x); o.y = f2bf(v.y); o.z = f2bf(v.z); o.w = f2bf(v.w);
    ((ushort4*)dst)[off] = o;
  }
  if (i0 < 3 * DM) {
    float v = (i0 < DM) ? qb[i0] : (i0 < 2 * DM ? kb[i0 - DM] : vb[i0 - 2 * DM]);
    bcat[i0] = v;
  }
}

// ---------------- 4-deep pipelined bf16 GEMM: C[M,N] = A[M,K] @ B[N,K]^T + bias ----------------
// BM=128, BN=256, BK=32. 512 thr = 8 waves (2M x 4N), per-wave C = 64x64 (4x4 frags).
// LDS 96KB = 4 bufs x (A[128][32] + B[256][32]); stage tile t+3 during tile t
// (targets buf (t-1)&3 whose readers finished before the last barrier -> race-free).
// One raw s_barrier + one counted vmcnt(6) per K-tile (T3+T4); drain only in 3-tile peel.
// Chunk swizzle: physical k-chunk = logical ^ ((row>>1)&3), identical on stage/read sides.
template <bool OUT_BF16>
__global__ __launch_bounds__(512, 2) void gemm_p4(const uint16_t* __restrict__ A,
                                                  const uint16_t* __restrict__ B,
                                                  const float* __restrict__ bias,
                                                  void* __restrict__ Cout,
                                                  int M, int N, int K) {
  __shared__ uint16_t sm[49152];   // 96 KiB

  const int tid = threadIdx.x;
  const int l   = tid & 63;
  const int wid = tid >> 6;        // 0..7
  const int wr  = wid >> 2;        // 0..1 (M half)
  const int wc  = wid & 3;         // 0..3 (N quarter)
  const int ln  = l & 15;
  const int g   = l >> 4;          // 0..3 (k-group)

  // T1: bijective XCD swizzle (nwg % 8 == 0 for all grids here)
  const int nbx = N >> 8;
  const int nwg = nbx * (M >> 7);
  const int bid = blockIdx.x;
  const int swz = (bid & 7) * (nwg >> 3) + (bid >> 3);
  const int m0  = (swz / nbx) << 7;
  const int n0  = (swz % nbx) << 8;

  // staging: per-lane global source (pre-swizzled chunk), wave-uniform LDS dst
  const int srow = l >> 2;                       // 0..15
  const int gch  = (l & 3) ^ ((l >> 3) & 3);     // (l&3) ^ ((row>>1)&3), row = wid*16+srow
  const uint16_t* pa  = A + (size_t)(m0 + wid * 16 + srow) * K + gch * 8;
  const uint16_t* pb0 = B + (size_t)(n0 + wid * 16 + srow) * K + gch * 8;
  const uint16_t* pb1 = B + (size_t)(n0 + 128 + wid * 16 + srow) * K + gch * 8;
  const int ldsA  = wid * 512;          // elems; buf = A[0,4096) | B[4096,12288)
  const int ldsB0 = 4096 + wid * 512;
  const int ldsB1 = 8192 + wid * 512;

  // read side: physical chunk (row = mult-of-16 + ln -> (row>>1)&3 == (ln>>1)&3)
  const int pc = g ^ ((ln >> 1) & 3);

  f32x4 acc[4][4];
#pragma unroll
  for (int i = 0; i < 4; ++i)
#pragma unroll
    for (int j = 0; j < 4; ++j) acc[i][j] = (f32x4){0.f, 0.f, 0.f, 0.f};

  const int nt = K >> 5;   // 64

#define STAGE(T)                                                        \
  {                                                                     \
    uint16_t* base_ = sm + (size_t)((T) & 3) * 12288;                   \
    const size_t ko_ = (size_t)(T) * 32;                                \
    gload_lds16(pa + ko_,  base_ + ldsA);                               \
    gload_lds16(pb0 + ko_, base_ + ldsB0);                              \
    gload_lds16(pb1 + ko_, base_ + ldsB1);                              \
  }

#define COMPUTE(T)                                                      \
  {                                                                     \
    const uint16_t* buf_ = sm + (size_t)((T) & 3) * 12288;              \
    short8 af_[4], bf_[4];                                              \
    _Pragma("unroll")                                                   \
    for (int fi = 0; fi < 4; ++fi)                                      \
      af_[fi] = *(const short8*)(buf_ + (wr * 64 + fi * 16 + ln) * 32 + pc * 8); \
    _Pragma("unroll")                                                   \
    for (int fj = 0; fj < 4; ++fj)                                      \
      bf_[fj] = *(const short8*)(buf_ + 4096 + (wc * 64 + fj * 16 + ln) * 32 + pc * 8); \
    __builtin_amdgcn_s_setprio(1);                                      \
    _Pragma("unroll")                                                   \
    for (int fi = 0; fi < 4; ++fi)                                      \
      _Pragma("unroll")                                                 \
      for (int fj = 0; fj < 4; ++fj)                                    \
        acc[fi][fj] = __builtin_amdgcn_mfma_f32_16x16x32_bf16(          \
            af_[fi], bf_[fj], acc[fi][fj], 0, 0, 0);                    \
    __builtin_amdgcn_s_setprio(0);                                      \
  }

  // prologue: tiles 0,1,2
  STAGE(0); STAGE(1); STAGE(2);
  asm volatile("s_waitcnt vmcnt(6)" ::: "memory");   // tile 0 landed
  __builtin_amdgcn_s_barrier();

#pragma unroll 1
  for (int t = 0; t < nt - 3; ++t) {
    STAGE(t + 3);                                    // -> buf (t-1)&3: safe
    COMPUTE(t);
    asm volatile("s_waitcnt vmcnt(6)" ::: "memory"); // tile t+1 landed
    __builtin_amdgcn_s_barrier();
  }
  COMPUTE(nt - 3);
  asm volatile("s_waitcnt vmcnt(3)" ::: "memory");
  __builtin_amdgcn_s_barrier();
  COMPUTE(nt - 2);
  asm volatile("s_waitcnt vmcnt(0)" ::: "memory");
  __builtin_amdgcn_s_barrier();
  COMPUTE(nt - 1);
#undef STAGE
#undef COMPUTE

  // epilogue: C/D layout col=lane&15, row=(lane>>4)*4+reg [m89, R2-verified]
  const int g4 = g * 4;
#pragma unroll
  for (int fi = 0; fi < 4; ++fi) {
    size_t row = (size_t)(m0 + wr * 64 + fi * 16 + g4);
#pragma unroll
    for (int fj = 0; fj < 4; ++fj) {
      int col = n0 + wc * 64 + fj * 16 + ln;
      float bv = bias[col];
#pragma unroll
      for (int r = 0; r < 4; ++r) {
        float v = acc[fi][fj][r] + bv;
        if (OUT_BF16) ((uint16_t*)Cout)[(row + r) * N + col] = f2bf(v);
        else          ((float*)Cout)[(row + r) * N + col] = v;
      }
    }
  }
}

// ---------------- MFMA windowed causal attention (unchanged, R2-verified) ----------------
__global__ __launch_bounds__(256) void attn_mfma(const uint16_t* __restrict__ QKV,
                                                 uint16_t* __restrict__ O) {
  __shared__ __align__(16) uint16_t smem[16384 + 17408];
  uint16_t* Qs = smem;
  uint16_t* Vt = smem + 16384;
  uint16_t* Pl = smem;

  const int tid  = threadIdx.x;
  const int lane = tid & 63;
  const int w    = tid >> 6;
  const int g    = lane >> 4;
  const int ln   = lane & 15;

  const int i0 = blockIdx.x * 64;
  const int h  = blockIdx.y;
  const int b  = blockIdx.z;
  const int wb = i0 - 63;
  const size_t hoff  = (size_t)h * HD;
  const size_t bbase = (size_t)b * TSEQ;

#pragma unroll
  for (int it = 0; it < 8; ++it) {
    int s   = it * 256 + tid;
    int row = s >> 4, c = s & 15;
    int j = wb + row;
    if (j >= 0 && j < TSEQ) {
      const uint16_t* gsrc = QKV + (bbase + j) * (size_t)QKV_LD + hoff
                           + (size_t)((c ^ (row & 7)) * 8);
      uint16_t* ldst = Qs + (size_t)(s & ~63) * 8;
      gload_lds16(gsrc, ldst);
    } else {
      uint4 z = {0, 0, 0, 0};
      *(uint4*)(Qs + (size_t)s * 8) = z;
    }
  }

#pragma unroll
  for (int it = 0; it < 4; ++it) {
    int s  = it * 256 + tid;
    int jp = (s & 15) | (it << 4);
    int dc = (s >> 4) & 15;
    int j0 = wb + 2 * jp;
    uint4 va = {0, 0, 0, 0}, vb = {0, 0, 0, 0};
    if (j0 >= 0 && j0 < TSEQ)
      va = *(const uint4*)(QKV + (bbase + j0) * (size_t)QKV_LD + 2 * DM + hoff + dc * 8);
    if (j0 + 1 >= 0 && j0 + 1 < TSEQ)
      vb = *(const uint4*)(QKV + (bbase + j0 + 1) * (size_t)QKV_LD + 2 * DM + hoff + dc * 8);
    const uint16_t* ap = (const uint16_t*)&va;
    const uint16_t* bp = (const uint16_t*)&vb;
#pragma unroll
    for (int t = 0; t < 8; ++t) {
      uint32_t pk = (uint32_t)ap[t] | ((uint32_t)bp[t] << 16);
      *(uint32_t*)(Vt + (size_t)(dc * 8 + t) * 136 + 2 * jp) = pk;
    }
  }

  short8 kreg[4];
  {
    const uint16_t* kp = QKV + (bbase + i0 + w * 16 + ln) * (size_t)QKV_LD
                       + DM + hoff + g * 8;
#pragma unroll
    for (int kc = 0; kc < 4; ++kc) kreg[kc] = *(const short8*)(kp + kc * 32);
  }

  __syncthreads();

  f32x4 acc[8];
#pragma unroll
  for (int nf = 0; nf < 8; ++nf) acc[nf] = (f32x4){0.f, 0.f, 0.f, 0.f};
#pragma unroll
  for (int kc = 0; kc < 4; ++kc) {
#pragma unroll
    for (int nf = 0; nf < 8; ++nf) {
      int row = nf * 16 + ln;
      int chunk = (kc * 4 + g) ^ (row & 7);
      short8 qf = *(const short8*)(Qs + (size_t)row * 128 + chunk * 8);
      acc[nf] = __builtin_amdgcn_mfma_f32_16x16x32_bf16(kreg[kc], qf, acc[nf], 0, 0, 0);
    }
  }

#pragma unroll
  for (int nf = 0; nf < 8; ++nf) {
    int rj = nf * 16 + ln;
    int jg = wb + rj;
#pragma unroll
    for (int r = 0; r < 4; ++r) {
      int il = w * 16 + g * 4 + r;
      int delta = il + 63 - rj;
      float v = acc[nf][r] * ATT_SCALE - (float)delta;
      acc[nf][r] = ((unsigned)delta < 64u && jg >= 0) ? v : -1e30f;
    }
  }

  float inv[4];
#pragma unroll
  for (int r = 0; r < 4; ++r) {
    float mx = acc[0][r];
#pragma unroll
    for (int nf = 1; nf < 8; ++nf) mx = fmaxf(mx, acc[nf][r]);
    mx = fmaxf(mx, __shfl_xor(mx, 1));
    mx = fmaxf(mx, __shfl_xor(mx, 2));
    mx = fmaxf(mx, __shfl_xor(mx, 4));
    mx = fmaxf(mx, __shfl_xor(mx, 8));
    float s = 0.f;
#pragma unroll
    for (int nf = 0; nf < 8; ++nf) {
      float e = __expf(acc[nf][r] - mx);
      acc[nf][r] = e;
      s += e;
    }
    s += __shfl_xor(s, 1);
    s += __shfl_xor(s, 2);
    s += __shfl_xor(s, 4);
    s += __shfl_xor(s, 8);
    inv[r] = 1.0f / s;
  }

  __syncthreads();

#pragma unroll
  for (int nf = 0; nf < 8; ++nf)
#pragma unroll
    for (int r = 0; r < 4; ++r)
      Pl[(size_t)(w * 16 + g * 4 + r) * 136 + nf * 16 + ln] = f2bf(acc[nf][r]);
  asm volatile("s_waitcnt lgkmcnt(0)" ::: "memory");
  __builtin_amdgcn_sched_barrier(0);

  f32x4 o[8];
#pragma unroll
  for (int nf = 0; nf < 8; ++nf) o[nf] = (f32x4){0.f, 0.f, 0.f, 0.f};
#pragma unroll
  for (int kc = 0; kc < 4; ++kc) {
    short8 pa = *(const short8*)(Pl + (size_t)(w * 16 + ln) * 136 + kc * 32 + g * 8);
#pragma unroll
    for (int nf = 0; nf < 8; ++nf) {
      short8 vbf = *(const short8*)(Vt + (size_t)(nf * 16 + ln) * 136 + kc * 32 + g * 8);
      o[nf] = __builtin_amdgcn_mfma_f32_16x16x32_bf16(pa, vbf, o[nf], 0, 0, 0);
    }
  }

  const size_t obase = (bbase + i0 + w * 16) * (size_t)DM + hoff;
#pragma unroll
  for (int nf = 0; nf < 8; ++nf)
#pragma unroll
    for (int r = 0; r < 4; ++r)
      O[obase + (size_t)(g * 4 + r) * DM + nf * 16 + ln] = f2bf(o[nf][r] * inv[r]);
}

// ---------------- launch ----------------
extern "C" void kernel_launch(void* const* d_in, const int* in_sizes, int n_in,
                              void* d_out, int out_size, void* d_ws, size_t ws_size,
                              hipStream_t stream) {
  const float* x   = (const float*)d_in[0];
  const float* q_w = (const float*)d_in[1];
  const float* q_b = (const float*)d_in[2];
  const float* k_w = (const float*)d_in[3];
  const float* k_b = (const float*)d_in[4];
  const float* v_w = (const float*)d_in[5];
  const float* v_b = (const float*)d_in[6];
  const float* o_w = (const float*)d_in[7];
  const float* o_b = (const float*)d_in[8];

  char* ws = (char*)d_ws;
  const size_t XB_BYTES   = (size_t)BT * DM * 2;
  const size_t W_BYTES    = (size_t)DM * DM * 2;
  const size_t WQKV_BYTES = 3 * W_BYTES;

  uint16_t* xb   = (uint16_t*)(ws);
  uint16_t* wqkv = (uint16_t*)(ws + XB_BYTES);
  uint16_t* wo   = (uint16_t*)(ws + XB_BYTES + WQKV_BYTES);
  float*    bcat = (float*)   (ws + XB_BYTES + WQKV_BYTES + W_BYTES);
  uint16_t* QKVb = (uint16_t*)(ws + XB_BYTES + WQKV_BYTES + W_BYTES + 24576);

  prep<<<2048, 256, 0, stream>>>(x, q_w, k_w, v_w, o_w, q_b, k_b, v_b,
                                 xb, wqkv, wo, bcat);

  // fused QKV projection: [4096][2048] @ [6144][2048]^T -> [4096][6144]
  gemm_p4<true><<<(BT / 128) * (3 * DM / 256), 512, 0, stream>>>(
      xb, wqkv, bcat, QKVb, BT, 3 * DM, DM);

  dim3 ga(TSEQ / 64, NHEAD, 2);
  attn_mfma<<<ga, 256, 0, stream>>>(QKVb, xb);

  gemm_p4<false><<<(BT / 128) * (DM / 256), 512, 0, stream>>>(
      xb, wo, o_b, d_out, BT, DM, DM);
}

// Round 5
// 202.693 us; speedup vs baseline: 1.5866x; 1.0197x over previous
//
#include <hip/hip_runtime.h>
#include <hip/hip_bf16.h>
#include <stdint.h>

// Problem constants (B=2, T=2048, D=2048, H=16, HD=128, ALPHA=1.0)
#define BT    4096
#define DM    2048
#define TSEQ  2048
#define NHEAD 16
#define HD    128
#define QKV_LD 6144
#define ATT_SCALE 0.088388347648318447f   // 128^-0.5
#define WIN   64

typedef __attribute__((ext_vector_type(8))) short short8;
typedef __attribute__((ext_vector_type(4))) float f32x4;

__device__ __forceinline__ uint16_t f2bf(float f) {
  uint32_t u = __float_as_uint(f);
  return (uint16_t)((u + 0x7FFFu + ((u >> 16) & 1u)) >> 16);  // RNE
}

__device__ __forceinline__ void gload_lds16(const void* g, void* l) {
  __builtin_amdgcn_global_load_lds((__attribute__((address_space(1))) void*)g,
                                   (__attribute__((address_space(3))) void*)l,
                                   16, 0, 0);
}

// ---------------- prep: all fp32->bf16 casts + bias concat, one launch ----------------
__global__ __launch_bounds__(256) void prep(const float* __restrict__ x,
                                            const float* __restrict__ qw,
                                            const float* __restrict__ kw,
                                            const float* __restrict__ vw,
                                            const float* __restrict__ ow,
                                            const float* __restrict__ qb,
                                            const float* __restrict__ kb,
                                            const float* __restrict__ vb,
                                            uint16_t* __restrict__ xb,
                                            uint16_t* __restrict__ wqkv,
                                            uint16_t* __restrict__ wo,
                                            float* __restrict__ bcat) {
  const int NX = BT * DM / 4;
  const int NW = DM * DM / 4;
  const int total = NX + 4 * NW;
  int i0 = blockIdx.x * 256 + threadIdx.x;
  for (int idx = i0; idx < total; idx += gridDim.x * 256) {
    const float* src;
    uint16_t* dst;
    int off;
    if (idx < NX)            { src = x;  dst = xb;                          off = idx; }
    else if (idx < NX + NW)  { src = qw; dst = wqkv;                        off = idx - NX; }
    else if (idx < NX + 2*NW){ src = kw; dst = wqkv + (size_t)DM * DM;      off = idx - NX - NW; }
    else if (idx < NX + 3*NW){ src = vw; dst = wqkv + (size_t)2 * DM * DM;  off = idx - NX - 2*NW; }
    else                     { src = ow; dst = wo;                          off = idx - NX - 3*NW; }
    float4 v = ((const float4*)src)[off];
    ushort4 o;
    o.x = f2bf(v.x); o.y = f2bf(v.y); o.z = f2bf(v.z); o.w = f2bf(v.w);
    ((ushort4*)dst)[off] = o;
  }
  if (i0 < 3 * DM) {
    float v = (i0 < DM) ? qb[i0] : (i0 < 2 * DM ? kb[i0 - DM] : vb[i0 - 2 * DM]);
    bcat[i0] = v;
  }
}

// ---------------- 4-deep pipelined bf16 GEMM: C[M,N] = A[M,K] @ B[N,K]^T + bias ----------------
// MF = A-fragments per wave: BM = MF*32 (128 or 256), BN=256, BK=32.
// 512 thr = 8 waves (2M x 4N), per-wave C = (MF*16) x 64. 4-buf LDS rotation,
// stage tile t+3 into buf (t-1)&3 (readers provably done) -> race-free [R4-verified].
// One raw s_barrier + one counted vmcnt per K-tile; drain only in the 3-tile peel.
// Chunk swizzle (R4-verified, 0 bank conflicts): phys chunk = logical ^ ((row>>1)&3).
// XCD-rect mapping: XCD x owns a compact (nbm/MB) x (nbx/NB) tile rectangle.
template <int MF, bool OUT_BF16>
__global__ __launch_bounds__(512, 1) void gemm_p4(const uint16_t* __restrict__ A,
                                                  const uint16_t* __restrict__ B,
                                                  const float* __restrict__ bias,
                                                  void* __restrict__ Cout,
                                                  int M, int N, int K) {
  constexpr int BM   = MF * 32;
  constexpr int ABUF = BM * 32;          // A elems per buf
  constexpr int BUFE = ABUF + 8192;      // + B 256x32
  constexpr int MB   = (MF == 8) ? 2 : 4;  // m-bands of XCD rects
  constexpr int NB   = 8 / MB;             // n-bands
  __shared__ uint16_t sm[4 * BUFE];      // 128 KiB (MF=8) / 96 KiB (MF=4)

  const int tid = threadIdx.x;
  const int l   = tid & 63;
  const int wid = tid >> 6;        // 0..7
  const int wr  = wid >> 2;        // 0..1 (M half)
  const int wc  = wid & 3;         // 0..3 (N quarter)
  const int ln  = l & 15;
  const int g   = l >> 4;          // 0..3 (k-group)

  // T1 XCD-rect: xcd = bid&7 owns rect (nbm/MB) x (nbx/NB); idx row-major n-fastest
  const int nbx    = N >> 8;
  const int bid    = blockIdx.x;
  const int xcd    = bid & 7;
  const int idx    = bid >> 3;
  const int rect_n = nbx / NB;
  const int rect_m = (M / BM) / MB;
  const int m_t    = (xcd / NB) * rect_m + idx / rect_n;
  const int n_t    = (xcd % NB) * rect_n + idx % rect_n;
  const int m0     = m_t * BM;
  const int n0     = n_t << 8;

  // staging: per-lane global source (pre-swizzled chunk), wave-uniform LDS dst
  const int srow = l >> 2;                       // 0..15
  const int gch  = (l & 3) ^ ((l >> 3) & 3);     // phys chunk for row = wid*16+srow
  const uint16_t* pa  = A + (size_t)(m0 + wid * 16 + srow) * K + gch * 8;
  const uint16_t* pb0 = B + (size_t)(n0 + wid * 16 + srow) * K + gch * 8;
  const uint16_t* pb1 = B + (size_t)(n0 + 128 + wid * 16 + srow) * K + gch * 8;
  const int ldsA  = wid * 512;
  const int ldsB0 = ABUF + wid * 512;
  const int ldsB1 = ABUF + 4096 + wid * 512;

  // read side: physical chunk (row = mult16 + ln -> (row>>1)&3 == (ln>>1)&3)
  const int pc = g ^ ((ln >> 1) & 3);

  f32x4 acc[MF][4];
#pragma unroll
  for (int i = 0; i < MF; ++i)
#pragma unroll
    for (int j = 0; j < 4; ++j) acc[i][j] = (f32x4){0.f, 0.f, 0.f, 0.f};

  const int nt = K >> 5;   // 64

#define STAGE(T)                                                        \
  {                                                                     \
    uint16_t* base_ = sm + (size_t)((T) & 3) * BUFE;                    \
    const size_t ko_ = (size_t)(T) * 32;                                \
    gload_lds16(pa + ko_, base_ + ldsA);                                \
    if (MF == 8) gload_lds16(pa + (size_t)128 * K + ko_, base_ + 4096 + ldsA); \
    gload_lds16(pb0 + ko_, base_ + ldsB0);                              \
    gload_lds16(pb1 + ko_, base_ + ldsB1);                              \
  }

#define COMPUTE(T)                                                      \
  {                                                                     \
    const uint16_t* buf_ = sm + (size_t)((T) & 3) * BUFE;               \
    short8 af_[MF], bf_[4];                                             \
    _Pragma("unroll")                                                   \
    for (int fi = 0; fi < MF; ++fi)                                     \
      af_[fi] = *(const short8*)(buf_ + (wr * (MF * 16) + fi * 16 + ln) * 32 + pc * 8); \
    _Pragma("unroll")                                                   \
    for (int fj = 0; fj < 4; ++fj)                                      \
      bf_[fj] = *(const short8*)(buf_ + ABUF + (wc * 64 + fj * 16 + ln) * 32 + pc * 8); \
    __builtin_amdgcn_s_setprio(1);                                      \
    _Pragma("unroll")                                                   \
    for (int fi = 0; fi < MF; ++fi)                                     \
      _Pragma("unroll")                                                 \
      for (int fj = 0; fj < 4; ++fj)                                    \
        acc[fi][fj] = __builtin_amdgcn_mfma_f32_16x16x32_bf16(          \
            af_[fi], bf_[fj], acc[fi][fj], 0, 0, 0);                    \
    __builtin_amdgcn_s_setprio(0);                                      \
  }

#define WAIT_LOOP()                                                     \
  if (MF == 8) asm volatile("s_waitcnt vmcnt(8)" ::: "memory");         \
  else         asm volatile("s_waitcnt vmcnt(6)" ::: "memory");
#define WAIT_PEEL1()                                                    \
  if (MF == 8) asm volatile("s_waitcnt vmcnt(4)" ::: "memory");         \
  else         asm volatile("s_waitcnt vmcnt(3)" ::: "memory");

  // prologue: tiles 0,1,2
  STAGE(0); STAGE(1); STAGE(2);
  WAIT_LOOP();                                     // tile 0 landed
  __builtin_amdgcn_s_barrier();

#pragma unroll 1
  for (int t = 0; t < nt - 3; ++t) {
    STAGE(t + 3);                                  // -> buf (t-1)&3: safe
    COMPUTE(t);
    WAIT_LOOP();                                   // tile t+1 landed
    __builtin_amdgcn_s_barrier();
  }
  COMPUTE(nt - 3);
  WAIT_PEEL1();
  __builtin_amdgcn_s_barrier();
  COMPUTE(nt - 2);
  asm volatile("s_waitcnt vmcnt(0)" ::: "memory");
  __builtin_amdgcn_s_barrier();
  COMPUTE(nt - 1);
#undef STAGE
#undef COMPUTE
#undef WAIT_LOOP
#undef WAIT_PEEL1

  // epilogue: C/D layout col=lane&15, row=(lane>>4)*4+reg [m89, R2-verified]
  const int g4 = g * 4;
#pragma unroll
  for (int fi = 0; fi < MF; ++fi) {
    size_t row = (size_t)(m0 + wr * (MF * 16) + fi * 16 + g4);
#pragma unroll
    for (int fj = 0; fj < 4; ++fj) {
      int col = n0 + wc * 64 + fj * 16 + ln;
      float bv = bias[col];
#pragma unroll
      for (int r = 0; r < 4; ++r) {
        float v = acc[fi][fj][r] + bv;
        if (OUT_BF16) ((uint16_t*)Cout)[(row + r) * N + col] = f2bf(v);
        else          ((float*)Cout)[(row + r) * N + col] = v;
      }
    }
  }
}

// ---------------- MFMA windowed causal attention (unchanged, R2-verified) ----------------
__global__ __launch_bounds__(256) void attn_mfma(const uint16_t* __restrict__ QKV,
                                                 uint16_t* __restrict__ O) {
  __shared__ __align__(16) uint16_t smem[16384 + 17408];
  uint16_t* Qs = smem;
  uint16_t* Vt = smem + 16384;
  uint16_t* Pl = smem;

  const int tid  = threadIdx.x;
  const int lane = tid & 63;
  const int w    = tid >> 6;
  const int g    = lane >> 4;
  const int ln   = lane & 15;

  const int i0 = blockIdx.x * 64;
  const int h  = blockIdx.y;
  const int b  = blockIdx.z;
  const int wb = i0 - 63;
  const size_t hoff  = (size_t)h * HD;
  const size_t bbase = (size_t)b * TSEQ;

#pragma unroll
  for (int it = 0; it < 8; ++it) {
    int s   = it * 256 + tid;
    int row = s >> 4, c = s & 15;
    int j = wb + row;
    if (j >= 0 && j < TSEQ) {
      const uint16_t* gsrc = QKV + (bbase + j) * (size_t)QKV_LD + hoff
                           + (size_t)((c ^ (row & 7)) * 8);
      uint16_t* ldst = Qs + (size_t)(s & ~63) * 8;
      gload_lds16(gsrc, ldst);
    } else {
      uint4 z = {0, 0, 0, 0};
      *(uint4*)(Qs + (size_t)s * 8) = z;
    }
  }

#pragma unroll
  for (int it = 0; it < 4; ++it) {
    int s  = it * 256 + tid;
    int jp = (s & 15) | (it << 4);
    int dc = (s >> 4) & 15;
    int j0 = wb + 2 * jp;
    uint4 va = {0, 0, 0, 0}, vb = {0, 0, 0, 0};
    if (j0 >= 0 && j0 < TSEQ)
      va = *(const uint4*)(QKV + (bbase + j0) * (size_t)QKV_LD + 2 * DM + hoff + dc * 8);
    if (j0 + 1 >= 0 && j0 + 1 < TSEQ)
      vb = *(const uint4*)(QKV + (bbase + j0 + 1) * (size_t)QKV_LD + 2 * DM + hoff + dc * 8);
    const uint16_t* ap = (const uint16_t*)&va;
    const uint16_t* bp = (const uint16_t*)&vb;
#pragma unroll
    for (int t = 0; t < 8; ++t) {
      uint32_t pk = (uint32_t)ap[t] | ((uint32_t)bp[t] << 16);
      *(uint32_t*)(Vt + (size_t)(dc * 8 + t) * 136 + 2 * jp) = pk;
    }
  }

  short8 kreg[4];
  {
    const uint16_t* kp = QKV + (bbase + i0 + w * 16 + ln) * (size_t)QKV_LD
                       + DM + hoff + g * 8;
#pragma unroll
    for (int kc = 0; kc < 4; ++kc) kreg[kc] = *(const short8*)(kp + kc * 32);
  }

  __syncthreads();

  f32x4 acc[8];
#pragma unroll
  for (int nf = 0; nf < 8; ++nf) acc[nf] = (f32x4){0.f, 0.f, 0.f, 0.f};
#pragma unroll
  for (int kc = 0; kc < 4; ++kc) {
#pragma unroll
    for (int nf = 0; nf < 8; ++nf) {
      int row = nf * 16 + ln;
      int chunk = (kc * 4 + g) ^ (row & 7);
      short8 qf = *(const short8*)(Qs + (size_t)row * 128 + chunk * 8);
      acc[nf] = __builtin_amdgcn_mfma_f32_16x16x32_bf16(kreg[kc], qf, acc[nf], 0, 0, 0);
    }
  }

#pragma unroll
  for (int nf = 0; nf < 8; ++nf) {
    int rj = nf * 16 + ln;
    int jg = wb + rj;
#pragma unroll
    for (int r = 0; r < 4; ++r) {
      int il = w * 16 + g * 4 + r;
      int delta = il + 63 - rj;
      float v = acc[nf][r] * ATT_SCALE - (float)delta;
      acc[nf][r] = ((unsigned)delta < 64u && jg >= 0) ? v : -1e30f;
    }
  }

  float inv[4];
#pragma unroll
  for (int r = 0; r < 4; ++r) {
    float mx = acc[0][r];
#pragma unroll
    for (int nf = 1; nf < 8; ++nf) mx = fmaxf(mx, acc[nf][r]);
    mx = fmaxf(mx, __shfl_xor(mx, 1));
    mx = fmaxf(mx, __shfl_xor(mx, 2));
    mx = fmaxf(mx, __shfl_xor(mx, 4));
    mx = fmaxf(mx, __shfl_xor(mx, 8));
    float s = 0.f;
#pragma unroll
    for (int nf = 0; nf < 8; ++nf) {
      float e = __expf(acc[nf][r] - mx);
      acc[nf][r] = e;
      s += e;
    }
    s += __shfl_xor(s, 1);
    s += __shfl_xor(s, 2);
    s += __shfl_xor(s, 4);
    s += __shfl_xor(s, 8);
    inv[r] = 1.0f / s;
  }

  __syncthreads();

#pragma unroll
  for (int nf = 0; nf < 8; ++nf)
#pragma unroll
    for (int r = 0; r < 4; ++r)
      Pl[(size_t)(w * 16 + g * 4 + r) * 136 + nf * 16 + ln] = f2bf(acc[nf][r]);
  asm volatile("s_waitcnt lgkmcnt(0)" ::: "memory");
  __builtin_amdgcn_sched_barrier(0);

  f32x4 o[8];
#pragma unroll
  for (int nf = 0; nf < 8; ++nf) o[nf] = (f32x4){0.f, 0.f, 0.f, 0.f};
#pragma unroll
  for (int kc = 0; kc < 4; ++kc) {
    short8 pa = *(const short8*)(Pl + (size_t)(w * 16 + ln) * 136 + kc * 32 + g * 8);
#pragma unroll
    for (int nf = 0; nf < 8; ++nf) {
      short8 vbf = *(const short8*)(Vt + (size_t)(nf * 16 + ln) * 136 + kc * 32 + g * 8);
      o[nf] = __builtin_amdgcn_mfma_f32_16x16x32_bf16(pa, vbf, o[nf], 0, 0, 0);
    }
  }

  const size_t obase = (bbase + i0 + w * 16) * (size_t)DM + hoff;
#pragma unroll
  for (int nf = 0; nf < 8; ++nf)
#pragma unroll
    for (int r = 0; r < 4; ++r)
      O[obase + (size_t)(g * 4 + r) * DM + nf * 16 + ln] = f2bf(o[nf][r] * inv[r]);
}

// ---------------- launch ----------------
extern "C" void kernel_launch(void* const* d_in, const int* in_sizes, int n_in,
                              void* d_out, int out_size, void* d_ws, size_t ws_size,
                              hipStream_t stream) {
  const float* x   = (const float*)d_in[0];
  const float* q_w = (const float*)d_in[1];
  const float* q_b = (const float*)d_in[2];
  const float* k_w = (const float*)d_in[3];
  const float* k_b = (const float*)d_in[4];
  const float* v_w = (const float*)d_in[5];
  const float* v_b = (const float*)d_in[6];
  const float* o_w = (const float*)d_in[7];
  const float* o_b = (const float*)d_in[8];

  char* ws = (char*)d_ws;
  const size_t XB_BYTES   = (size_t)BT * DM * 2;
  const size_t W_BYTES    = (size_t)DM * DM * 2;
  const size_t WQKV_BYTES = 3 * W_BYTES;

  uint16_t* xb   = (uint16_t*)(ws);
  uint16_t* wqkv = (uint16_t*)(ws + XB_BYTES);
  uint16_t* wo   = (uint16_t*)(ws + XB_BYTES + WQKV_BYTES);
  float*    bcat = (float*)   (ws + XB_BYTES + WQKV_BYTES + W_BYTES);
  uint16_t* QKVb = (uint16_t*)(ws + XB_BYTES + WQKV_BYTES + W_BYTES + 24576);

  prep<<<2048, 256, 0, stream>>>(x, q_w, k_w, v_w, o_w, q_b, k_b, v_b,
                                 xb, wqkv, wo, bcat);

  // fused QKV projection: [4096][2048] @ [6144][2048]^T -> [4096][6144]
  // BM=256: 16x24 = 384 blocks, XCD rect 8m x 6n
  gemm_p4<8, true><<<(BT / 256) * (3 * DM / 256), 512, 0, stream>>>(
      xb, wqkv, bcat, QKVb, BT, 3 * DM, DM);

  dim3 ga(TSEQ / 64, NHEAD, 2);
  attn_mfma<<<ga, 256, 0, stream>>>(QKVb, xb);

  // O projection: BM=128: 32x8 = 256 blocks (full chip), XCD rect 8m x 4n
  gemm_p4<4, false><<<(BT / 128) * (DM / 256), 512, 0, stream>>>(
      xb, wo, o_b, d_out, BT, DM, DM);
}